// Round 11
// baseline (161.987 us; speedup 1.0000x reference)
//
#include <hip/hip_runtime.h>

#define N_TOK 32768
#define D 256
#define DFF 1024
#define NE 8
#define TB 64    // tokens per expert_ffn block

typedef __attribute__((ext_vector_type(16))) float f32x16;
typedef __attribute__((ext_vector_type(8)))  short bf16x8;

// Raw barrier: LDS writes made visible (lgkmcnt(0)) but NO vmcnt drain --
// in-flight global weight loads survive the barrier (T3/T4; verified r8).
#define BARRIER() do {                                        \
    asm volatile("s_waitcnt lgkmcnt(0)" ::: "memory");        \
    __builtin_amdgcn_s_barrier();                             \
    __builtin_amdgcn_sched_barrier(0);                        \
} while (0)

// fp32 -> bf16 round-to-nearest-even
__device__ __forceinline__ unsigned short f2bf(float f) {
    union { float f; unsigned u; } v; v.f = f;
    unsigned r = v.u + 0x7FFFu + ((v.u >> 16) & 1u);
    return (unsigned short)(r >> 16);
}

// ===========================================================================
// Fused prep + gate (1 launch). Blocks [0,1024): w1 prep; [1024,2048): w2
// prep; [2048,2176): gate (thread-per-token fp64 logits, top-2, softmax,
// hierarchical binning). Layout conventions verified rounds 2-10:
//  w1f: frag=(e*32+fblk)*16+dblk; elem f=fblk*32+(l&31), d=dblk*16+(l>>5)*8+j
//  w2f: frag=(e*8+cblk)*64+fblk; elem col=cblk*32+(l&31), f=fblk*16+(l>>5)*8+j
// ===========================================================================
__global__ __launch_bounds__(256) void prep_gate(
    const float* __restrict__ w1, const float* __restrict__ w2,
    short* __restrict__ w1f, short* __restrict__ w2f,
    const float* __restrict__ x, const float* __restrict__ gw,
    const float* __restrict__ gb,
    int* __restrict__ cnt, int* __restrict__ bidx, float* __restrict__ bp,
    int2* __restrict__ opos) {
    const int b = blockIdx.x;
    if (b < 2048) {
        // ---------------- weight prep ----------------
        if (b < 1024) {
            const int gid  = b * 256 + threadIdx.x;
            const int lane = gid & 63;
            const int frag = gid >> 6;
            const int dblk = frag & 15;
            const int fblk = (frag >> 4) & 31;
            const int e    = frag >> 9;
            const int l31 = lane & 31, g = lane >> 5;

            const float* src = w1 + ((size_t)e * 256 + dblk * 16 + g * 8) * 1024
                                  + fblk * 32 + l31;
            unsigned u[4];
#pragma unroll
            for (int jp = 0; jp < 4; ++jp) {
                float a = src[(size_t)(jp * 2)     * 1024];
                float c = src[(size_t)(jp * 2 + 1) * 1024];
                u[jp] = (unsigned)f2bf(a) | ((unsigned)f2bf(c) << 16);
            }
            *(uint4*)(w1f + (size_t)gid * 8) = make_uint4(u[0], u[1], u[2], u[3]);
        } else {
            const int gid  = (b - 1024) * 256 + threadIdx.x;
            const int lane = gid & 63;
            const int frag = gid >> 6;
            const int fblk = frag & 63;
            const int cblk = (frag >> 6) & 7;
            const int e    = frag >> 9;
            const int l31 = lane & 31, g = lane >> 5;

            const float* src = w2 + ((size_t)e * 1024 + fblk * 16 + g * 8) * 256
                                  + cblk * 32 + l31;
            unsigned u[4];
#pragma unroll
            for (int jp = 0; jp < 4; ++jp) {
                float a = src[(size_t)(jp * 2)     * 256];
                float c = src[(size_t)(jp * 2 + 1) * 256];
                u[jp] = (unsigned)f2bf(a) | ((unsigned)f2bf(c) << 16);
            }
            *(uint4*)(w2f + (size_t)gid * 8) = make_uint4(u[0], u[1], u[2], u[3]);
        }
        return;
    }

    // ---------------- gate ----------------
    __shared__ float gws[2048];   // [d][e]
    __shared__ int   se1[256], se2[256];
    __shared__ float sp1[256], sp2[256];
    __shared__ int   hist[NE], base_[NE];

    const int tid = threadIdx.x;
#pragma unroll
    for (int i = 0; i < 8; ++i) gws[tid + 256 * i] = gw[tid + 256 * i];
    if (tid < NE) hist[tid] = 0;
    __syncthreads();

    const int t = (b - 2048) * 256 + tid;
    const float* xr = x + (size_t)t * D;

    double acc[NE];
#pragma unroll
    for (int e = 0; e < NE; ++e) acc[e] = 0.0;

    for (int d0 = 0; d0 < 256; d0 += 4) {
        float4 xv = *(const float4*)(xr + d0);
        float xa[4] = {xv.x, xv.y, xv.z, xv.w};
#pragma unroll
        for (int j = 0; j < 4; ++j) {
            float4 ga  = *(const float4*)&gws[(d0 + j) * 8];
            float4 gbb = *(const float4*)&gws[(d0 + j) * 8 + 4];
            double xd = (double)xa[j];
            acc[0] += xd * (double)ga.x;  acc[1] += xd * (double)ga.y;
            acc[2] += xd * (double)ga.z;  acc[3] += xd * (double)ga.w;
            acc[4] += xd * (double)gbb.x; acc[5] += xd * (double)gbb.y;
            acc[6] += xd * (double)gbb.z; acc[7] += xd * (double)gbb.w;
        }
    }

    double l[NE];
#pragma unroll
    for (int e = 0; e < NE; ++e) l[e] = acc[e] + (double)gb[e];
    int e1 = 0;
#pragma unroll
    for (int e = 1; e < NE; ++e) if (l[e] > l[e1]) e1 = e;
    int e2 = (e1 == 0) ? 1 : 0;
#pragma unroll
    for (int e = 0; e < NE; ++e) if (e != e1 && l[e] > l[e2]) e2 = e;

    double s = 0.0;
#pragma unroll
    for (int e = 0; e < NE; ++e) s += exp(l[e] - l[e1]);
    se1[tid] = e1; se2[tid] = e2;
    sp1[tid] = (float)(1.0 / s);
    sp2[tid] = (float)(exp(l[e2] - l[e1]) / s);
    __syncthreads();

    const int pos1 = atomicAdd(&hist[se1[tid]], 1);
    const int pos2 = atomicAdd(&hist[se2[tid]], 1);
    __syncthreads();
    if (tid < NE) base_[tid] = atomicAdd(&cnt[tid], hist[tid]);
    __syncthreads();

    const int o1 = se1[tid] * N_TOK + base_[se1[tid]] + pos1;
    const int o2 = se2[tid] * N_TOK + base_[se2[tid]] + pos2;
    bidx[o1] = t;  bp[o1] = sp1[tid];
    bidx[o2] = t;  bp[o2] = sp2[tid];
    opos[t] = make_int2(o1, o2);
}

// ===========================================================================
// Expert FFN v11 = v10 geometry + DEEP GLOBAL PREFETCH (the v10 residual:
// weight loads rolled only 1 iter (~30cyc) ahead of ~200cyc L2 latency).
//  - w1: 4-deep rolling ring; next-fc's first 4 frags issued at GEMM2 start
//    (lead = entire GEMM2 phase; survives raw barriers - no vmcnt drain).
//  - w2: 4-deep ring; first 4 issued before pack (lead = pack + barrier).
//  - LDS reads stay 1-deep (120cyc covered by 4 waves/SIMD).
//  - frag = 4 VGPR, so rings cost +16 regs; peak ~125 < 128 cliff (m69).
// 512 thr / 8 waves, TB=64, fchunk=256, LDS 64.8KB, 2 blocks/CU, 16 w/CU.
// Layouts / pack / epilogue verbatim from verified rounds 2-10.
// ===========================================================================
__global__ __launch_bounds__(512, 4) void expert_ffn(
    const float* __restrict__ x,
    const short* __restrict__ w1f,
    const short* __restrict__ w2f,
    const float* __restrict__ b1, const float* __restrict__ b2,
    const int* __restrict__ cnt, const int* __restrict__ bidx,
    const float* __restrict__ bp, float* __restrict__ out,
    float* __restrict__ yp, int staged) {
    const int e    = blockIdx.x & 7;
    const int tile = blockIdx.x >> 3;
    const int n_e  = cnt[e];
    const int row0 = tile * TB;
    if (row0 >= n_e) return;

    __shared__ short xs[16 * 64 * 16];   // 32KB [dblk][tok64][16] frag-major
    __shared__ short hs[32 * 512];       // 32KB [frag(kt*2+tp)][512]
    __shared__ int   tok_s[TB];
    __shared__ float p_s[TB];

    const int tid  = threadIdx.x;
    const int lane = tid & 63, wid = tid >> 6;   // wid 0..7
    const int l31  = lane & 31, g = lane >> 5;

    if (tid < TB) {
        int r = row0 + tid;
        tok_s[tid] = (r < n_e) ? bidx[e * N_TOK + r] : -1;
        p_s[tid]   = (r < n_e) ? bp[e * N_TOK + r] : 0.f;
    }
    BARRIER();

    // ---- stage x -> xs (bf16 frag-major): element (tok, d=db*16+g*8+j)
    // at xs[db*1024 + tok*16 + g*8 + j]. 512 thr: tok=tid>>3, 2 dblks each.
    {
        const int tok = tid >> 3;
        const int tk  = tok_s[tok];
        const float* xrow = x + (size_t)(tk < 0 ? 0 : tk) * D;
#pragma unroll
        for (int i = 0; i < 2; ++i) {
            const int dblk = (tid & 7) * 2 + i;
            unsigned u[8];
            if (tk >= 0) {
#pragma unroll
                for (int q = 0; q < 4; ++q) {
                    float4 v = *(const float4*)(xrow + dblk * 16 + q * 4);
                    u[q * 2 + 0] = (unsigned)f2bf(v.x) | ((unsigned)f2bf(v.y) << 16);
                    u[q * 2 + 1] = (unsigned)f2bf(v.z) | ((unsigned)f2bf(v.w) << 16);
                }
            } else {
#pragma unroll
                for (int q = 0; q < 8; ++q) u[q] = 0;
            }
            short* dp = &xs[dblk * 1024 + tok * 16];
            *(uint4*)(dp)     = make_uint4(u[0], u[1], u[2], u[3]);
            *(uint4*)(dp + 8) = make_uint4(u[4], u[5], u[6], u[7]);
        }
    }

    f32x16 acc[2];   // [tp tok-half], cols wid*32 + l31
#pragma unroll
    for (int a = 0; a < 2; ++a)
#pragma unroll
        for (int r = 0; r < 16; ++r) acc[a][r] = 0.f;

    const short* w1e = w1f + (size_t)e * (32 * 16 * 512);
    const short* w2e = w2f + (size_t)e * (8 * 64 * 512);
    const float* b1e = b1 + e * DFF;

    // ---- prologue: 4-deep w1 ring for fc=0 (lives across fc iterations;
    // refilled for fc+1 during GEMM2 of fc)
    bf16x8 w1r[4];
    {
        const short* w1p0 = w1e + ((size_t)(0 * 8 + wid) * 16) * 512 + lane * 8;
#pragma unroll
        for (int k = 0; k < 4; ++k) w1r[k] = *(const bf16x8*)(w1p0 + k * 512);
    }

    BARRIER();   // xs ready

    for (int fc = 0; fc < 4; ++fc) {
        const short* w1p = w1e + ((size_t)(fc * 8 + wid) * 16) * 512 + lane * 8;

        // ---------- GEMM1: wave wid -> f-strip [fc*256+wid*32, +32) x 64 tok
        f32x16 h0, h1;
#pragma unroll
        for (int r = 0; r < 16; ++r) { h0[r] = 0.f; h1[r] = 0.f; }

        __builtin_amdgcn_s_setprio(1);
        {
            bf16x8 x0 = *(const bf16x8*)&xs[l31 * 16 + g * 8];
            bf16x8 x1 = *(const bf16x8*)&xs[512 + l31 * 16 + g * 8];
#pragma unroll
            for (int db = 0; db < 16; ++db) {
                bf16x8 wa = w1r[db & 3];
                if (db < 12)
                    w1r[db & 3] = *(const bf16x8*)(w1p + (db + 4) * 512);
                bf16x8 y0, y1;
                if (db < 15) {
                    y0 = *(const bf16x8*)&xs[(db + 1) * 1024 + l31 * 16 + g * 8];
                    y1 = *(const bf16x8*)&xs[(db + 1) * 1024 + 512 + l31 * 16 + g * 8];
                }
                h0 = __builtin_amdgcn_mfma_f32_32x32x16_bf16(wa, x0, h0, 0, 0, 0);
                h1 = __builtin_amdgcn_mfma_f32_32x32x16_bf16(wa, x1, h1, 0, 0, 0);
                if (db < 15) { x0 = y0; x1 = y1; }
            }
        }
        __builtin_amdgcn_s_setprio(0);

        // ---------- issue w2 ring (first 4) now: pack + barrier hide latency
        const short* w2p = w2e + ((size_t)wid * 64 + fc * 16) * 512 + lane * 8;
        bf16x8 w2r[4];
#pragma unroll
        for (int k = 0; k < 4; ++k) w2r[k] = *(const bf16x8*)(w2p + k * 512);

        BARRIER();   // prev GEMM2 hs reads done; in-flight vmem survives

        // ---------- pack: bias+relu+bf16 -> hs frag-major (verbatim r5-r10)
#pragma unroll
        for (int tp = 0; tp < 2; ++tp) {
            const f32x16& hh = tp ? h1 : h0;
#pragma unroll
            for (int m = 0; m < 4; ++m) {
                float4 bq = *(const float4*)(b1e + fc * 256 + wid * 32 + 8 * m + 4 * g);
                float v0 = fmaxf(hh[4 * m + 0] + bq.x, 0.f);
                float v1 = fmaxf(hh[4 * m + 1] + bq.y, 0.f);
                float v2 = fmaxf(hh[4 * m + 2] + bq.z, 0.f);
                float v3 = fmaxf(hh[4 * m + 3] + bq.w, 0.f);
                uint2 pk;
                pk.x = (unsigned)f2bf(v0) | ((unsigned)f2bf(v1) << 16);
                pk.y = (unsigned)f2bf(v2) | ((unsigned)f2bf(v3) << 16);
                const int fragid = (2 * wid + (m >> 1)) * 2 + tp;
                *(uint2*)&hs[fragid * 512 + ((m & 1) * 32 + l31) * 8 + 4 * g] = pk;
            }
        }

        BARRIER();   // hs ready; in-flight vmem survives

        // ---------- refill w1 ring for fc+1 (lead = whole GEMM2 phase)
        if (fc < 3) {
            const short* w1n = w1e + ((size_t)((fc + 1) * 8 + wid) * 16) * 512 + lane * 8;
#pragma unroll
            for (int k = 0; k < 4; ++k) w1r[k] = *(const bf16x8*)(w1n + k * 512);
        }

        // ---------- GEMM2: wave wid -> cols [wid*32, +32), k over 256 f
        __builtin_amdgcn_s_setprio(1);
        {
            bf16x8 ha0 = *(const bf16x8*)&hs[0 * 512 + lane * 8];
            bf16x8 ha1 = *(const bf16x8*)&hs[1 * 512 + lane * 8];
#pragma unroll
            for (int kt = 0; kt < 16; ++kt) {
                bf16x8 wa = w2r[kt & 3];
                if (kt < 12)
                    w2r[kt & 3] = *(const bf16x8*)(w2p + (kt + 4) * 512);
                bf16x8 hb0, hb1;
                if (kt < 15) {
                    hb0 = *(const bf16x8*)&hs[((kt + 1) * 2 + 0) * 512 + lane * 8];
                    hb1 = *(const bf16x8*)&hs[((kt + 1) * 2 + 1) * 512 + lane * 8];
                }
                acc[0] = __builtin_amdgcn_mfma_f32_32x32x16_bf16(ha0, wa, acc[0], 0, 0, 0);
                acc[1] = __builtin_amdgcn_mfma_f32_32x32x16_bf16(ha1, wa, acc[1], 0, 0, 0);
                if (kt < 15) { ha0 = hb0; ha1 = hb1; }
            }
        }
        __builtin_amdgcn_s_setprio(0);
    }

    // ---- epilogue ----
    const float* b2e = b2 + e * D;
    const int col = wid * 32 + l31;
    const float bv = b2e[col];
    if (staged) {
        float* ype = yp + ((size_t)e * N_TOK + row0) * 256;
#pragma unroll
        for (int tp = 0; tp < 2; ++tp) {
#pragma unroll
            for (int r = 0; r < 16; ++r) {
                const int tl = tp * 32 + (r & 3) + 8 * (r >> 2) + 4 * g;
                if (tok_s[tl] >= 0)
                    __builtin_nontemporal_store(
                        (acc[tp][r] + bv) * p_s[tl],
                        &ype[(size_t)tl * 256 + col]);
            }
        }
    } else {
#pragma unroll
        for (int tp = 0; tp < 2; ++tp) {
#pragma unroll
            for (int r = 0; r < 16; ++r) {
                const int tl = tp * 32 + (r & 3) + 8 * (r >> 2) + 4 * g;
                const int tk = tok_s[tl];
                if (tk >= 0)
                    atomicAdd(out + (size_t)tk * D + col,
                              (acc[tp][r] + bv) * p_s[tl]);
            }
        }
    }
}

// ===========================================================================
// Combine: out[t] = yp[o1] + yp[o2]. One wave per token row.
// ===========================================================================
__global__ __launch_bounds__(256) void combine(
    const float* __restrict__ yp, const int2* __restrict__ opos,
    float* __restrict__ out) {
    const int gid   = blockIdx.x * 256 + threadIdx.x;  // float4 index
    const int t     = gid >> 6;
    const int lane4 = gid & 63;
    const int2 o = opos[t];
    const float4 a = ((const float4*)yp)[(size_t)o.x * 64 + lane4];
    const float4 b = ((const float4*)yp)[(size_t)o.y * 64 + lane4];
    float4 r;
    r.x = a.x + b.x; r.y = a.y + b.y; r.z = a.z + b.z; r.w = a.w + b.w;
    ((float4*)out)[gid] = r;
}

// ---------------------------------------------------------------------------
extern "C" void kernel_launch(void* const* d_in, const int* in_sizes, int n_in,
                              void* d_out, int out_size, void* d_ws, size_t ws_size,
                              hipStream_t stream) {
    const float* x  = (const float*)d_in[0];
    const float* gw = (const float*)d_in[1];
    const float* gb = (const float*)d_in[2];
    const float* w1 = (const float*)d_in[3];
    const float* b1 = (const float*)d_in[4];
    const float* w2 = (const float*)d_in[5];
    const float* b2 = (const float*)d_in[6];
    float* out = (float*)d_out;

    // ws: cnt 256B | bidx 1MB | bp 1MB | opos 512KB | w1f 4MB | w2f 4MB
    //   | yp 64MB (staged partials).
    char* ws = (char*)d_ws;
    size_t off = 0;
    int*   cnt   = (int*)(ws + off);  off += 256;
    int*   bidx  = (int*)(ws + off);  off += (size_t)NE * N_TOK * 4;
    float* bp    = (float*)(ws + off); off += (size_t)NE * N_TOK * 4;
    int2*  opos  = (int2*)(ws + off); off += (size_t)N_TOK * 8;
    short* w1f   = (short*)(ws + off); off += (size_t)NE * D * DFF * 2;
    short* w2f   = (short*)(ws + off); off += (size_t)NE * D * DFF * 2;
    float* yp    = (float*)(ws + off); off += (size_t)2 * N_TOK * D * 4;
    const int staged = (ws_size >= off) ? 1 : 0;

    hipMemsetAsync(cnt, 0, 256, stream);
    if (!staged)
        hipMemsetAsync(d_out, 0, (size_t)out_size * sizeof(float), stream);

    // fused: weight prep (2048 blocks) + gate (128 blocks), one launch
    prep_gate<<<2048 + N_TOK / 256, 256, 0, stream>>>(
        w1, w2, w1f, w2f, x, gw, gb, cnt, bidx, bp, opos);
    expert_ffn<<<NE * (N_TOK / TB), 512, 0, stream>>>(x, w1f, w2f, b1, b2,
                                                      cnt, bidx, bp, out, yp, staged);
    if (staged)
        combine<<<(N_TOK * D / 4) / 256, 256, 0, stream>>>(yp, opos, out);
}